// Round 3
// baseline (4255.108 us; speedup 1.0000x reference)
//
#include <hip/hip_runtime.h>
#include <hip/hip_bf16.h>
#include <stdint.h>

#define H 1024
#define BATCH 64
#define TSTEPS 64
#define VOCAB 32000

typedef __attribute__((ext_vector_type(8))) short bf16x8;
typedef __attribute__((ext_vector_type(4))) float f32x4;

__device__ __forceinline__ uint16_t f2b(float f) {
  union { float f; uint32_t u; } v; v.f = f;
  uint32_t u = v.u;
  return (uint16_t)((u + 0x7FFFu + ((u >> 16) & 1u)) >> 16);
}

__device__ __forceinline__ void g2l16(const uint16_t* g, uint16_t* l) {
  __builtin_amdgcn_global_load_lds((const __attribute__((address_space(1))) void*)(g),
                                   (__attribute__((address_space(3))) void*)(l), 16, 0, 0);
}

// ---- f32 -> bf16 cast (n4 = n/4) ----
__global__ void cast_bf16_kernel(const float* __restrict__ src, uint16_t* __restrict__ dst, int n4) {
  int i = blockIdx.x * blockDim.x + threadIdx.x;
  int stride = gridDim.x * blockDim.x;
  for (; i < n4; i += stride) {
    float4 f = ((const float4*)src)[i];
    union { uint16_t u[4]; uint64_t d; } o;
    o.u[0] = f2b(f.x); o.u[1] = f2b(f.y); o.u[2] = f2b(f.z); o.u[3] = f2b(f.w);
    ((uint64_t*)dst)[i] = o.d;
  }
}

// ---- embed + relu -> bf16, X[t*64+b][H] ----
__global__ void embed_kernel(const float* __restrict__ emb, const int* __restrict__ tgt,
                             uint16_t* __restrict__ X) {
  int i = blockIdx.x;            // 0..4095 = t*64+b
  int t = i >> 6, b = i & 63;
  int tok = (t == 0) ? 0 : tgt[b * TSTEPS + (t - 1)];
  const float4* src = (const float4*)(emb + (size_t)tok * H);
  uint64_t* dst = (uint64_t*)(X + (size_t)i * H);
  int k = threadIdx.x;           // 256 threads x 4 elems
  float4 f = src[k];
  union { uint16_t u[4]; uint64_t d; } o;
  o.u[0] = f2b(fmaxf(f.x, 0.f)); o.u[1] = f2b(fmaxf(f.y, 0.f));
  o.u[2] = f2b(fmaxf(f.z, 0.f)); o.u[3] = f2b(fmaxf(f.w, 0.f));
  dst[k] = o.d;
}

// ---- h0 init: cast enc_hidden to bf16 into Hsb[0] ----
__global__ void h0_kernel(const float* __restrict__ eh, uint16_t* __restrict__ hb0) {
  int i = blockIdx.x * blockDim.x + threadIdx.x;   // 16384 threads x 4
  float4 f = ((const float4*)eh)[i];
  union { uint16_t u[4]; uint64_t d; } o;
  o.u[0] = f2b(f.x); o.u[1] = f2b(f.y); o.u[2] = f2b(f.z); o.u[3] = f2b(f.w);
  ((uint64_t*)hb0)[i] = o.d;
}

__global__ void barinit_kernel(unsigned* __restrict__ bar) {
  bar[threadIdx.x + blockIdx.x * 256] = 0u;
}

// ---- gi GEMM: gi = relu(emb)@W_ih^T + b_ih, row-major [4096][3072] f32 ----
__global__ __launch_bounds__(256) void gi_gemm_kernel(
    const uint16_t* __restrict__ A,    // [4096][1024]
    const uint16_t* __restrict__ Bm,   // [3072][1024]
    const float* __restrict__ bias,    // [3072]
    float* __restrict__ out) {         // [4096][3072]
  __shared__ uint16_t lA[128 * 32];
  __shared__ uint16_t lB[128 * 32];
  const int tid = threadIdx.x;
  const int lane = tid & 63;
  const int w = tid >> 6;
  const int wr = w >> 1, wc = w & 1;
  int flat = blockIdx.y * 24 + blockIdx.x;       // 768 blocks
  int nf = (flat & 7) * 96 + (flat >> 3);        // XCD swizzle (768 % 8 == 0)
  const int m0 = (nf / 24) * 128;
  const int n0 = (nf % 24) * 128;

  f32x4 acc[4][4];
#pragma unroll
  for (int mi = 0; mi < 4; ++mi)
#pragma unroll
    for (int ni = 0; ni < 4; ++ni) acc[mi][ni] = (f32x4){0, 0, 0, 0};

  const int srow = w * 16 + (lane >> 2);
  const int scol = (lane & 3) * 8;

  for (int k0 = 0; k0 < 1024; k0 += 32) {
    __syncthreads();
    g2l16(A + (size_t)(m0 + srow) * 1024 + k0 + scol,       &lA[w * 512]);
    g2l16(A + (size_t)(m0 + 64 + srow) * 1024 + k0 + scol,  &lA[2048 + w * 512]);
    g2l16(Bm + (size_t)(n0 + srow) * 1024 + k0 + scol,      &lB[w * 512]);
    g2l16(Bm + (size_t)(n0 + 64 + srow) * 1024 + k0 + scol, &lB[2048 + w * 512]);
    __syncthreads();
    bf16x8 a[4], b[4];
#pragma unroll
    for (int mi = 0; mi < 4; ++mi)
      a[mi] = *(const bf16x8*)&lA[(wr * 64 + mi * 16 + (lane & 15)) * 32 + (lane >> 4) * 8];
#pragma unroll
    for (int ni = 0; ni < 4; ++ni)
      b[ni] = *(const bf16x8*)&lB[(wc * 64 + ni * 16 + (lane & 15)) * 32 + (lane >> 4) * 8];
#pragma unroll
    for (int mi = 0; mi < 4; ++mi)
#pragma unroll
      for (int ni = 0; ni < 4; ++ni)
        acc[mi][ni] = __builtin_amdgcn_mfma_f32_16x16x32_bf16(a[mi], b[ni], acc[mi][ni], 0, 0, 0);
  }

#pragma unroll
  for (int ni = 0; ni < 4; ++ni) {
    int v = n0 + wc * 64 + ni * 16 + (lane & 15);
    float bv = bias[v];
#pragma unroll
    for (int mi = 0; mi < 4; ++mi) {
#pragma unroll
      for (int r = 0; r < 4; ++r) {
        int row = m0 + wr * 64 + mi * 16 + (lane >> 4) * 4 + r;
        out[(size_t)row * 3072 + v] = acc[mi][ni][r] + bv;
      }
    }
  }
}

// ---- persistent recurrence: 256 blocks x 4 waves, W_hh slice in registers ----
// block owns h-cols [c0, c0+4); per wave: m-tile of 16 rows, one 16-col gate tile
// packed [r0..3, z0..3, n0..3, pad4]. One grid barrier per step.
__global__ __launch_bounds__(256, 2) void recur_kernel(
    const uint16_t* __restrict__ Whh_b,   // [3072][1024] bf16
    const float* __restrict__ gi,         // [4096][3072] f32 (incl b_ih)
    const float* __restrict__ b_hh,       // [3072]
    const float* __restrict__ h0f,        // [64][1024] f32
    uint16_t* __restrict__ Hsb,           // [65][64][1024] bf16
    float* __restrict__ hfin,             // [64][1024] f32 (d_out tail)
    unsigned* __restrict__ bar) {
  const int tid = threadIdx.x, lane = tid & 63, w = tid >> 6;
  const int blk = blockIdx.x;
  const int c0 = blk * 4;
  const int r15 = lane & 15;
  const int kq = lane >> 4;

  // B fragments (W_hh slice) -> registers; rows 12-15 are dummies (never consumed)
  bf16x8 bf[32];
  {
    int grow = (r15 < 12) ? ((r15 >> 2) * 1024 + c0 + (r15 & 3)) : (2048 + c0 + 3);
    const uint16_t* bp = Whh_b + (size_t)grow * 1024 + kq * 8;
#pragma unroll
    for (int kk = 0; kk < 32; ++kk) bf[kk] = *(const bf16x8*)(bp + kk * 32);
  }

  const int c = r15;       // active gate-col lane when c<4
  const int hi = kq;
  float hreg[4] = {0, 0, 0, 0};
  float bhr = 0, bhz = 0, bhn = 0;
  if (c < 4) {
    bhr = b_hh[c0 + c]; bhz = b_hh[1024 + c0 + c]; bhn = b_hh[2048 + c0 + c];
#pragma unroll
    for (int rr = 0; rr < 4; ++rr)
      hreg[rr] = h0f[(size_t)(w * 16 + hi * 4 + rr) * 1024 + c0 + c];
  }
  const int arow = w * 16 + r15;
  const int g = blk >> 4;

  for (int t = 0; t < TSTEPS; ++t) {
    // prefetch gi (token-only, independent of h)
    float gr[4], gz[4], gn[4];
    if (c < 4) {
      const float* gp = gi + (size_t)(t * 64 + w * 16 + hi * 4) * 3072 + c0 + c;
#pragma unroll
      for (int rr = 0; rr < 4; ++rr) {
        gr[rr] = gp[(size_t)rr * 3072];
        gz[rr] = gp[(size_t)rr * 3072 + 1024];
        gn[rr] = gp[(size_t)rr * 3072 + 2048];
      }
    }
    // gh = h_{t-1} @ Whh_slice^T
    const uint16_t* ap = Hsb + (size_t)(t * 64 + arow) * 1024 + kq * 8;
    f32x4 acc = {0, 0, 0, 0};
#pragma unroll
    for (int kk = 0; kk < 32; ++kk) {
      bf16x8 a = *(const bf16x8*)(ap + kk * 32);
      acc = __builtin_amdgcn_mfma_f32_16x16x32_bf16(a, bf[kk], acc, 0, 0, 0);
    }
    // gather z,n partial sums from companion lanes
    int base = lane & 48;
    int cc = lane & 3;
    f32x4 zacc, nacc;
#pragma unroll
    for (int e = 0; e < 4; ++e) {
      zacc[e] = __shfl(acc[e], base + 4 + cc);
      nacc[e] = __shfl(acc[e], base + 8 + cc);
    }
    if (c < 4) {
#pragma unroll
      for (int rr = 0; rr < 4; ++rr) {
        float rg = 1.f / (1.f + __expf(-(gr[rr] + acc[rr] + bhr)));
        float zg = 1.f / (1.f + __expf(-(gz[rr] + zacc[rr] + bhz)));
        float ng = tanhf(gn[rr] + rg * (nacc[rr] + bhn));
        float hnew = (1.f - zg) * ng + zg * hreg[rr];
        hreg[rr] = hnew;
        Hsb[(size_t)((t + 1) * 64 + w * 16 + hi * 4 + rr) * 1024 + c0 + c] = f2b(hnew);
      }
    }
    // ---- grid barrier (2-level, monotonic counters) ----
    __threadfence();
    __syncthreads();
    if (tid == 0) {
      unsigned a1 = __hip_atomic_fetch_add(&bar[g * 32], 1u, __ATOMIC_ACQ_REL, __HIP_MEMORY_SCOPE_AGENT);
      if (a1 == (unsigned)(16 * t + 15)) {
        unsigned a2 = __hip_atomic_fetch_add(&bar[512], 1u, __ATOMIC_ACQ_REL, __HIP_MEMORY_SCOPE_AGENT);
        if (a2 == (unsigned)(16 * t + 15))
          __hip_atomic_store(&bar[544], (unsigned)(t + 1), __ATOMIC_RELEASE, __HIP_MEMORY_SCOPE_AGENT);
      }
      while (__hip_atomic_load(&bar[544], __ATOMIC_ACQUIRE, __HIP_MEMORY_SCOPE_AGENT) < (unsigned)(t + 1))
        __builtin_amdgcn_s_sleep(2);
    }
    __syncthreads();
    __threadfence();
  }
  if (c < 4) {
#pragma unroll
    for (int rr = 0; rr < 4; ++rr)
      hfin[(size_t)(w * 16 + hi * 4 + rr) * 1024 + c0 + c] = hreg[rr];
  }
}

// ---- big output GEMM with XCD swizzle + non-temporal stores ----
__global__ __launch_bounds__(256) void out_gemm_kernel(
    const uint16_t* __restrict__ A,    // [4096][1024]  (Hsb+65536)
    const uint16_t* __restrict__ Bm,   // [32000][1024]
    const float* __restrict__ bias,    // [32000]
    float* __restrict__ out) {
  __shared__ uint16_t lA[128 * 32];
  __shared__ uint16_t lB[128 * 32];
  const int tid = threadIdx.x;
  const int lane = tid & 63;
  const int w = tid >> 6;
  const int wr = w >> 1, wc = w & 1;
  int flat = blockIdx.y * 250 + blockIdx.x;        // 8000 blocks
  int nf = (flat & 7) * 1000 + (flat >> 3);        // XCD swizzle (8000 % 8 == 0)
  const int m0 = (nf / 250) * 128;
  const int n0 = (nf % 250) * 128;

  f32x4 acc[4][4];
#pragma unroll
  for (int mi = 0; mi < 4; ++mi)
#pragma unroll
    for (int ni = 0; ni < 4; ++ni) acc[mi][ni] = (f32x4){0, 0, 0, 0};

  const int srow = w * 16 + (lane >> 2);
  const int scol = (lane & 3) * 8;

  for (int k0 = 0; k0 < 1024; k0 += 32) {
    __syncthreads();
    g2l16(A + (size_t)(m0 + srow) * 1024 + k0 + scol,       &lA[w * 512]);
    g2l16(A + (size_t)(m0 + 64 + srow) * 1024 + k0 + scol,  &lA[2048 + w * 512]);
    g2l16(Bm + (size_t)(n0 + srow) * 1024 + k0 + scol,      &lB[w * 512]);
    g2l16(Bm + (size_t)(n0 + 64 + srow) * 1024 + k0 + scol, &lB[2048 + w * 512]);
    __syncthreads();
    bf16x8 a[4], b[4];
#pragma unroll
    for (int mi = 0; mi < 4; ++mi)
      a[mi] = *(const bf16x8*)&lA[(wr * 64 + mi * 16 + (lane & 15)) * 32 + (lane >> 4) * 8];
#pragma unroll
    for (int ni = 0; ni < 4; ++ni)
      b[ni] = *(const bf16x8*)&lB[(wc * 64 + ni * 16 + (lane & 15)) * 32 + (lane >> 4) * 8];
#pragma unroll
    for (int mi = 0; mi < 4; ++mi)
#pragma unroll
      for (int ni = 0; ni < 4; ++ni)
        acc[mi][ni] = __builtin_amdgcn_mfma_f32_16x16x32_bf16(a[mi], b[ni], acc[mi][ni], 0, 0, 0);
  }

#pragma unroll
  for (int ni = 0; ni < 4; ++ni) {
    int v = n0 + wc * 64 + ni * 16 + (lane & 15);
    float bv = bias[v];
#pragma unroll
    for (int mi = 0; mi < 4; ++mi) {
#pragma unroll
      for (int r = 0; r < 4; ++r) {
        int row = m0 + wr * 64 + mi * 16 + (lane >> 4) * 4 + r;  // row = t*64+b
        size_t off = (size_t)(row & 63) * (TSTEPS * (size_t)VOCAB)
                   + (size_t)(row >> 6) * VOCAB + v;
        __builtin_nontemporal_store(acc[mi][ni][r] + bv, &out[off]);
      }
    }
  }
}

// ---- in-place log_softmax over rows of 32000 ----
__global__ __launch_bounds__(256) void lsm_kernel(float* __restrict__ out) {
  float* row = out + (size_t)blockIdx.x * VOCAB;
  const int tid = threadIdx.x;
  float m = -3.4e38f, s = 0.f;
  for (int i = tid * 4; i < VOCAB; i += 1024) {
    float4 x = *(const float4*)(row + i);
    float lm = fmaxf(fmaxf(x.x, x.y), fmaxf(x.z, x.w));
    if (lm > m) { s *= expf(m - lm); m = lm; }
    s += expf(x.x - m) + expf(x.y - m) + expf(x.z - m) + expf(x.w - m);
  }
#pragma unroll
  for (int off = 32; off > 0; off >>= 1) {
    float m2 = __shfl_xor(m, off);
    float s2 = __shfl_xor(s, off);
    float mn = fmaxf(m, m2);
    s = s * expf(m - mn) + s2 * expf(m2 - mn);
    m = mn;
  }
  __shared__ float sm[4], ss[4];
  if ((tid & 63) == 0) { sm[tid >> 6] = m; ss[tid >> 6] = s; }
  __syncthreads();
  float M = fmaxf(fmaxf(sm[0], sm[1]), fmaxf(sm[2], sm[3]));
  float S = ss[0] * expf(sm[0] - M) + ss[1] * expf(sm[1] - M)
          + ss[2] * expf(sm[2] - M) + ss[3] * expf(sm[3] - M);
  float lse = M + logf(S);
  for (int i = tid * 4; i < VOCAB; i += 1024) {
    f32x4 x = *(const f32x4*)(row + i);
    x[0] -= lse; x[1] -= lse; x[2] -= lse; x[3] -= lse;
    __builtin_nontemporal_store(x, (f32x4*)(row + i));
  }
}

extern "C" void kernel_launch(void* const* d_in, const int* in_sizes, int n_in,
                              void* d_out, int out_size, void* d_ws, size_t ws_size,
                              hipStream_t stream) {
  const float* enc_hidden = (const float*)d_in[1];   // [1,64,1024]
  const int* tgt          = (const int*)d_in[2];     // [64,64]
  const float* emb        = (const float*)d_in[3];   // [32000,1024]
  const float* W_ih       = (const float*)d_in[4];   // [3072,1024]
  const float* W_hh       = (const float*)d_in[5];   // [3072,1024]
  const float* b_ih       = (const float*)d_in[6];   // [3072]
  const float* b_hh       = (const float*)d_in[7];   // [3072]
  const float* W_out      = (const float*)d_in[8];   // [32000,1024]
  const float* b_out      = (const float*)d_in[9];   // [32000]
  float* out = (float*)d_out;

  char* ws = (char*)d_ws;
  // region [0, 65536000): gi (50.3 MB, used before out-GEMM) then Wout_b (cast after recur)
  float*    gi     = (float*)(ws);
  uint16_t* Wout_b = (uint16_t*)(ws);
  uint16_t* Wih_b  = (uint16_t*)(ws + 65536000);      // 6,291,456
  uint16_t* Whh_b  = (uint16_t*)(ws + 71827456);      // 6,291,456
  uint16_t* Xb     = (uint16_t*)(ws + 78118912);      // 8,388,608
  uint16_t* Hsb    = (uint16_t*)(ws + 86507520);      // 8,519,680  [65][64][1024]
  unsigned* bar    = (unsigned*)(ws + 95027200);      // 8,192      (total 95,035,392)

  cast_bf16_kernel<<<2048, 256, 0, stream>>>(W_ih, Wih_b, 3072 * 1024 / 4);
  cast_bf16_kernel<<<2048, 256, 0, stream>>>(W_hh, Whh_b, 3072 * 1024 / 4);
  embed_kernel<<<4096, 256, 0, stream>>>(emb, tgt, Xb);
  h0_kernel<<<64, 256, 0, stream>>>(enc_hidden, Hsb);
  barinit_kernel<<<8, 256, 0, stream>>>(bar);

  dim3 gg(24, 32);
  gi_gemm_kernel<<<gg, 256, 0, stream>>>(Xb, Wih_b, b_ih, gi);

  recur_kernel<<<256, 256, 0, stream>>>(Whh_b, gi, b_hh, enc_hidden, Hsb,
                                        out + 131072000ull, bar);

  cast_bf16_kernel<<<2048, 256, 0, stream>>>(W_out, Wout_b, VOCAB * 1024 / 4);

  dim3 g(250, 32);
  out_gemm_kernel<<<g, 256, 0, stream>>>(Hsb + 65536, Wout_b, b_out, out);
  lsm_kernel<<<4096, 256, 0, stream>>>(out);
}

// Round 4
// 1165.750 us; speedup vs baseline: 3.6501x; 3.6501x over previous
//
#include <hip/hip_runtime.h>
#include <hip/hip_bf16.h>
#include <stdint.h>

#define H 1024
#define BATCH 64
#define TSTEPS 64
#define VOCAB 32000

typedef __attribute__((ext_vector_type(8))) short bf16x8;
typedef __attribute__((ext_vector_type(4))) float f32x4;

__device__ __forceinline__ uint16_t f2b(float f) {
  union { float f; uint32_t u; } v; v.f = f;
  uint32_t u = v.u;
  return (uint16_t)((u + 0x7FFFu + ((u >> 16) & 1u)) >> 16);
}

__device__ __forceinline__ void g2l16(const uint16_t* g, uint16_t* l) {
  __builtin_amdgcn_global_load_lds((const __attribute__((address_space(1))) void*)(g),
                                   (__attribute__((address_space(3))) void*)(l), 16, 0, 0);
}

// ---- f32 -> bf16 cast (n4 = n/4) ----
__global__ void cast_bf16_kernel(const float* __restrict__ src, uint16_t* __restrict__ dst, int n4) {
  int i = blockIdx.x * blockDim.x + threadIdx.x;
  int stride = gridDim.x * blockDim.x;
  for (; i < n4; i += stride) {
    float4 f = ((const float4*)src)[i];
    union { uint16_t u[4]; uint64_t d; } o;
    o.u[0] = f2b(f.x); o.u[1] = f2b(f.y); o.u[2] = f2b(f.z); o.u[3] = f2b(f.w);
    ((uint64_t*)dst)[i] = o.d;
  }
}

// ---- embed + relu -> bf16, X[t*64+b][H] ----
__global__ void embed_kernel(const float* __restrict__ emb, const int* __restrict__ tgt,
                             uint16_t* __restrict__ X) {
  int i = blockIdx.x;            // 0..4095 = t*64+b
  int t = i >> 6, b = i & 63;
  int tok = (t == 0) ? 0 : tgt[b * TSTEPS + (t - 1)];
  const float4* src = (const float4*)(emb + (size_t)tok * H);
  uint64_t* dst = (uint64_t*)(X + (size_t)i * H);
  int k = threadIdx.x;           // 256 threads x 4 elems
  float4 f = src[k];
  union { uint16_t u[4]; uint64_t d; } o;
  o.u[0] = f2b(fmaxf(f.x, 0.f)); o.u[1] = f2b(fmaxf(f.y, 0.f));
  o.u[2] = f2b(fmaxf(f.z, 0.f)); o.u[3] = f2b(fmaxf(f.w, 0.f));
  dst[k] = o.d;
}

// ---- h0 init: cast enc_hidden to bf16 into Hsb[0] ----
__global__ void h0_kernel(const float* __restrict__ eh, uint16_t* __restrict__ hb0) {
  int i = blockIdx.x * blockDim.x + threadIdx.x;   // 16384 threads x 4
  float4 f = ((const float4*)eh)[i];
  union { uint16_t u[4]; uint64_t d; } o;
  o.u[0] = f2b(f.x); o.u[1] = f2b(f.y); o.u[2] = f2b(f.z); o.u[3] = f2b(f.w);
  ((uint64_t*)hb0)[i] = o.d;
}

// ---- gi GEMM: gi = relu(emb)@W_ih^T + b_ih, row-major [4096][3072] f32 ----
__global__ __launch_bounds__(256) void gi_gemm_kernel(
    const uint16_t* __restrict__ A,    // [4096][1024]
    const uint16_t* __restrict__ Bm,   // [3072][1024]
    const float* __restrict__ bias,    // [3072]
    float* __restrict__ out) {         // [4096][3072]
  __shared__ uint16_t lA[128 * 32];
  __shared__ uint16_t lB[128 * 32];
  const int tid = threadIdx.x;
  const int lane = tid & 63;
  const int w = tid >> 6;
  const int wr = w >> 1, wc = w & 1;
  int flat = blockIdx.y * 24 + blockIdx.x;       // 768 blocks
  int nf = (flat & 7) * 96 + (flat >> 3);        // XCD swizzle (768 % 8 == 0)
  const int m0 = (nf / 24) * 128;
  const int n0 = (nf % 24) * 128;

  f32x4 acc[4][4];
#pragma unroll
  for (int mi = 0; mi < 4; ++mi)
#pragma unroll
    for (int ni = 0; ni < 4; ++ni) acc[mi][ni] = (f32x4){0, 0, 0, 0};

  const int srow = w * 16 + (lane >> 2);
  const int scol = (lane & 3) * 8;

  for (int k0 = 0; k0 < 1024; k0 += 32) {
    __syncthreads();
    g2l16(A + (size_t)(m0 + srow) * 1024 + k0 + scol,       &lA[w * 512]);
    g2l16(A + (size_t)(m0 + 64 + srow) * 1024 + k0 + scol,  &lA[2048 + w * 512]);
    g2l16(Bm + (size_t)(n0 + srow) * 1024 + k0 + scol,      &lB[w * 512]);
    g2l16(Bm + (size_t)(n0 + 64 + srow) * 1024 + k0 + scol, &lB[2048 + w * 512]);
    __syncthreads();
    bf16x8 a[4], b[4];
#pragma unroll
    for (int mi = 0; mi < 4; ++mi)
      a[mi] = *(const bf16x8*)&lA[(wr * 64 + mi * 16 + (lane & 15)) * 32 + (lane >> 4) * 8];
#pragma unroll
    for (int ni = 0; ni < 4; ++ni)
      b[ni] = *(const bf16x8*)&lB[(wc * 64 + ni * 16 + (lane & 15)) * 32 + (lane >> 4) * 8];
#pragma unroll
    for (int mi = 0; mi < 4; ++mi)
#pragma unroll
      for (int ni = 0; ni < 4; ++ni)
        acc[mi][ni] = __builtin_amdgcn_mfma_f32_16x16x32_bf16(a[mi], b[ni], acc[mi][ni], 0, 0, 0);
  }

#pragma unroll
  for (int ni = 0; ni < 4; ++ni) {
    int v = n0 + wc * 64 + ni * 16 + (lane & 15);
    float bv = bias[v];
#pragma unroll
    for (int mi = 0; mi < 4; ++mi) {
#pragma unroll
      for (int r = 0; r < 4; ++r) {
        int row = m0 + wr * 64 + mi * 16 + (lane >> 4) * 4 + r;
        out[(size_t)row * 3072 + v] = acc[mi][ni][r] + bv;
      }
    }
  }
}

// ---- one GRU step, gh-only: 256 blocks x 64 threads (1 wave) ----
// block = (16 batch rows) x (16 h-cols): rg = blk>>6, cs = blk&63
// 3 MFMA chains (r,z,n gates), then gate math + h update.
__global__ __launch_bounds__(64) void step_kernel(
    const uint16_t* __restrict__ Whh_b,  // [3072][1024] bf16
    const float* __restrict__ gi,        // [4096][3072] f32 (incl b_ih)
    const float* __restrict__ b_hh,      // [3072]
    const float* __restrict__ h_cur,     // [64][1024] f32
    float* __restrict__ h_nxt,           // [64][1024] f32
    uint16_t* __restrict__ Hsb,          // [65][64][1024] bf16
    int t) {
  const int lane = threadIdx.x;
  const int l15 = lane & 15, kq = lane >> 4;
  const int rg = blockIdx.x >> 6, cs = blockIdx.x & 63;
  const int m0 = rg * 16, c0 = cs * 16;
  const int c = c0 + l15;

  // prefetch gi + h_old for this lane's 4 output rows
  float gr[4], gz[4], gn[4], hold[4];
#pragma unroll
  for (int r = 0; r < 4; ++r) {
    int m = m0 + kq * 4 + r;
    const float* gp = gi + (size_t)(t * 64 + m) * 3072;
    gr[r] = gp[c]; gz[r] = gp[1024 + c]; gn[r] = gp[2048 + c];
    hold[r] = h_cur[(size_t)m * 1024 + c];
  }

  const uint16_t* ap = Hsb + (size_t)(t * 64 + m0 + l15) * 1024 + kq * 8;
  const uint16_t* br = Whh_b + (size_t)(c) * 1024 + kq * 8;
  const uint16_t* bz = Whh_b + (size_t)(1024 + c) * 1024 + kq * 8;
  const uint16_t* bn = Whh_b + (size_t)(2048 + c) * 1024 + kq * 8;

  f32x4 ar = {0,0,0,0}, az = {0,0,0,0}, an = {0,0,0,0};
#pragma unroll
  for (int kk = 0; kk < 32; ++kk) {
    bf16x8 a = *(const bf16x8*)(ap + kk * 32);
    ar = __builtin_amdgcn_mfma_f32_16x16x32_bf16(a, *(const bf16x8*)(br + kk * 32), ar, 0, 0, 0);
    az = __builtin_amdgcn_mfma_f32_16x16x32_bf16(a, *(const bf16x8*)(bz + kk * 32), az, 0, 0, 0);
    an = __builtin_amdgcn_mfma_f32_16x16x32_bf16(a, *(const bf16x8*)(bn + kk * 32), an, 0, 0, 0);
  }

  float bhr = b_hh[c], bhz = b_hh[1024 + c], bhn = b_hh[2048 + c];
#pragma unroll
  for (int r = 0; r < 4; ++r) {
    int m = m0 + kq * 4 + r;
    float rg_ = 1.f / (1.f + __expf(-(gr[r] + ar[r] + bhr)));
    float zg  = 1.f / (1.f + __expf(-(gz[r] + az[r] + bhz)));
    float ng  = tanhf(gn[r] + rg_ * (an[r] + bhn));
    float hnew = (1.f - zg) * ng + zg * hold[r];
    h_nxt[(size_t)m * 1024 + c] = hnew;
    Hsb[(size_t)((t + 1) * 64 + m) * 1024 + c] = f2b(hnew);
  }
}

// ---- big output GEMM with XCD swizzle + non-temporal stores ----
__global__ __launch_bounds__(256) void out_gemm_kernel(
    const uint16_t* __restrict__ A,    // [4096][1024]  (Hsb+65536)
    const uint16_t* __restrict__ Bm,   // [32000][1024]
    const float* __restrict__ bias,    // [32000]
    float* __restrict__ out) {
  __shared__ uint16_t lA[128 * 32];
  __shared__ uint16_t lB[128 * 32];
  const int tid = threadIdx.x;
  const int lane = tid & 63;
  const int w = tid >> 6;
  const int wr = w >> 1, wc = w & 1;
  int flat = blockIdx.y * 250 + blockIdx.x;        // 8000 blocks
  int nf = (flat & 7) * 1000 + (flat >> 3);        // XCD swizzle (8000 % 8 == 0)
  const int m0 = (nf / 250) * 128;
  const int n0 = (nf % 250) * 128;

  f32x4 acc[4][4];
#pragma unroll
  for (int mi = 0; mi < 4; ++mi)
#pragma unroll
    for (int ni = 0; ni < 4; ++ni) acc[mi][ni] = (f32x4){0, 0, 0, 0};

  const int srow = w * 16 + (lane >> 2);
  const int scol = (lane & 3) * 8;

  for (int k0 = 0; k0 < 1024; k0 += 32) {
    __syncthreads();
    g2l16(A + (size_t)(m0 + srow) * 1024 + k0 + scol,       &lA[w * 512]);
    g2l16(A + (size_t)(m0 + 64 + srow) * 1024 + k0 + scol,  &lA[2048 + w * 512]);
    g2l16(Bm + (size_t)(n0 + srow) * 1024 + k0 + scol,      &lB[w * 512]);
    g2l16(Bm + (size_t)(n0 + 64 + srow) * 1024 + k0 + scol, &lB[2048 + w * 512]);
    __syncthreads();
    bf16x8 a[4], b[4];
#pragma unroll
    for (int mi = 0; mi < 4; ++mi)
      a[mi] = *(const bf16x8*)&lA[(wr * 64 + mi * 16 + (lane & 15)) * 32 + (lane >> 4) * 8];
#pragma unroll
    for (int ni = 0; ni < 4; ++ni)
      b[ni] = *(const bf16x8*)&lB[(wc * 64 + ni * 16 + (lane & 15)) * 32 + (lane >> 4) * 8];
#pragma unroll
    for (int mi = 0; mi < 4; ++mi)
#pragma unroll
      for (int ni = 0; ni < 4; ++ni)
        acc[mi][ni] = __builtin_amdgcn_mfma_f32_16x16x32_bf16(a[mi], b[ni], acc[mi][ni], 0, 0, 0);
  }

#pragma unroll
  for (int ni = 0; ni < 4; ++ni) {
    int v = n0 + wc * 64 + ni * 16 + (lane & 15);
    float bv = bias[v];
#pragma unroll
    for (int mi = 0; mi < 4; ++mi) {
#pragma unroll
      for (int r = 0; r < 4; ++r) {
        int row = m0 + wr * 64 + mi * 16 + (lane >> 4) * 4 + r;  // row = t*64+b
        size_t off = (size_t)(row & 63) * (TSTEPS * (size_t)VOCAB)
                   + (size_t)(row >> 6) * VOCAB + v;
        __builtin_nontemporal_store(acc[mi][ni][r] + bv, &out[off]);
      }
    }
  }
}

// ---- in-place log_softmax over rows of 32000 ----
__global__ __launch_bounds__(256) void lsm_kernel(float* __restrict__ out) {
  float* row = out + (size_t)blockIdx.x * VOCAB;
  const int tid = threadIdx.x;
  float m = -3.4e38f, s = 0.f;
  for (int i = tid * 4; i < VOCAB; i += 1024) {
    float4 x = *(const float4*)(row + i);
    float lm = fmaxf(fmaxf(x.x, x.y), fmaxf(x.z, x.w));
    if (lm > m) { s *= expf(m - lm); m = lm; }
    s += expf(x.x - m) + expf(x.y - m) + expf(x.z - m) + expf(x.w - m);
  }
#pragma unroll
  for (int off = 32; off > 0; off >>= 1) {
    float m2 = __shfl_xor(m, off);
    float s2 = __shfl_xor(s, off);
    float mn = fmaxf(m, m2);
    s = s * expf(m - mn) + s2 * expf(m2 - mn);
    m = mn;
  }
  __shared__ float sm[4], ss[4];
  if ((tid & 63) == 0) { sm[tid >> 6] = m; ss[tid >> 6] = s; }
  __syncthreads();
  float M = fmaxf(fmaxf(sm[0], sm[1]), fmaxf(sm[2], sm[3]));
  float S = ss[0] * expf(sm[0] - M) + ss[1] * expf(sm[1] - M)
          + ss[2] * expf(sm[2] - M) + ss[3] * expf(sm[3] - M);
  float lse = M + logf(S);
  for (int i = tid * 4; i < VOCAB; i += 1024) {
    f32x4 x = *(const f32x4*)(row + i);
    x[0] -= lse; x[1] -= lse; x[2] -= lse; x[3] -= lse;
    __builtin_nontemporal_store(x, (f32x4*)(row + i));
  }
}

__global__ void hcopy_kernel(const float* __restrict__ h, float* __restrict__ out) {
  int i = blockIdx.x * blockDim.x + threadIdx.x;
  ((float4*)out)[i] = ((const float4*)h)[i];
}

extern "C" void kernel_launch(void* const* d_in, const int* in_sizes, int n_in,
                              void* d_out, int out_size, void* d_ws, size_t ws_size,
                              hipStream_t stream) {
  const float* enc_hidden = (const float*)d_in[1];   // [1,64,1024]
  const int* tgt          = (const int*)d_in[2];     // [64,64]
  const float* emb        = (const float*)d_in[3];   // [32000,1024]
  const float* W_ih       = (const float*)d_in[4];   // [3072,1024]
  const float* W_hh       = (const float*)d_in[5];   // [3072,1024]
  const float* b_ih       = (const float*)d_in[6];   // [3072]
  const float* b_hh       = (const float*)d_in[7];   // [3072]
  const float* W_out      = (const float*)d_in[8];   // [32000,1024]
  const float* b_out      = (const float*)d_in[9];   // [32000]
  float* out = (float*)d_out;

  char* ws = (char*)d_ws;
  // region [0, 65536000): gi (50.3 MB, live through recurrence) then Wout_b (cast after)
  float*    gi     = (float*)(ws);
  uint16_t* Wout_b = (uint16_t*)(ws);
  uint16_t* Wih_b  = (uint16_t*)(ws + 65536000);      // 6,291,456
  uint16_t* Whh_b  = (uint16_t*)(ws + 71827456);      // 6,291,456
  uint16_t* Xb     = (uint16_t*)(ws + 78118912);      // 8,388,608
  uint16_t* Hsb    = (uint16_t*)(ws + 86507520);      // 8,519,680  [65][64][1024]
  float*    hA     = (float*)   (ws + 95027200);      // 262,144
  float*    hB     = (float*)   (ws + 95289344);      // 262,144  (total 95,551,488)

  cast_bf16_kernel<<<2048, 256, 0, stream>>>(W_ih, Wih_b, 3072 * 1024 / 4);
  cast_bf16_kernel<<<2048, 256, 0, stream>>>(W_hh, Whh_b, 3072 * 1024 / 4);
  embed_kernel<<<4096, 256, 0, stream>>>(emb, tgt, Xb);
  h0_kernel<<<64, 256, 0, stream>>>(enc_hidden, Hsb);

  dim3 gg(24, 32);
  gi_gemm_kernel<<<gg, 256, 0, stream>>>(Xb, Wih_b, b_ih, gi);

  for (int t = 0; t < TSTEPS; ++t) {
    const float* hc = (t == 0) ? enc_hidden : ((t & 1) ? hA : hB);
    float* hn       = (t & 1) ? hB : hA;
    step_kernel<<<256, 64, 0, stream>>>(Whh_b, gi, b_hh, hc, hn, Hsb, t);
  }

  cast_bf16_kernel<<<2048, 256, 0, stream>>>(W_out, Wout_b, VOCAB * 1024 / 4);

  dim3 g(250, 32);
  out_gemm_kernel<<<g, 256, 0, stream>>>(Hsb + 65536, Wout_b, b_out, out);
  lsm_kernel<<<4096, 256, 0, stream>>>(out);
  hcopy_kernel<<<64, 256, 0, stream>>>((TSTEPS & 1) ? hB : hA, out + 131072000ull);
}

// Round 5
// 1114.663 us; speedup vs baseline: 3.8174x; 1.0458x over previous
//
#include <hip/hip_runtime.h>
#include <hip/hip_bf16.h>
#include <stdint.h>

#define H 1024
#define BATCH 64
#define TSTEPS 64
#define VOCAB 32000

typedef __attribute__((ext_vector_type(8))) short bf16x8;
typedef __attribute__((ext_vector_type(4))) float f32x4;

__device__ __forceinline__ uint16_t f2b(float f) {
  union { float f; uint32_t u; } v; v.f = f;
  uint32_t u = v.u;
  return (uint16_t)((u + 0x7FFFu + ((u >> 16) & 1u)) >> 16);
}

__device__ __forceinline__ void g2l16(const uint16_t* g, uint16_t* l) {
  __builtin_amdgcn_global_load_lds((const __attribute__((address_space(1))) void*)(g),
                                   (__attribute__((address_space(3))) void*)(l), 16, 0, 0);
}

// ---- f32 -> bf16 cast (n4 = n/4) ----
__global__ void cast_bf16_kernel(const float* __restrict__ src, uint16_t* __restrict__ dst, int n4) {
  int i = blockIdx.x * blockDim.x + threadIdx.x;
  int stride = gridDim.x * blockDim.x;
  for (; i < n4; i += stride) {
    float4 f = ((const float4*)src)[i];
    union { uint16_t u[4]; uint64_t d; } o;
    o.u[0] = f2b(f.x); o.u[1] = f2b(f.y); o.u[2] = f2b(f.z); o.u[3] = f2b(f.w);
    ((uint64_t*)dst)[i] = o.d;
  }
}

// ---- embed + relu -> bf16, X[t*64+b][H] ----
__global__ void embed_kernel(const float* __restrict__ emb, const int* __restrict__ tgt,
                             uint16_t* __restrict__ X) {
  int i = blockIdx.x;            // 0..4095 = t*64+b
  int t = i >> 6, b = i & 63;
  int tok = (t == 0) ? 0 : tgt[b * TSTEPS + (t - 1)];
  const float4* src = (const float4*)(emb + (size_t)tok * H);
  uint64_t* dst = (uint64_t*)(X + (size_t)i * H);
  int k = threadIdx.x;           // 256 threads x 4 elems
  float4 f = src[k];
  union { uint16_t u[4]; uint64_t d; } o;
  o.u[0] = f2b(fmaxf(f.x, 0.f)); o.u[1] = f2b(fmaxf(f.y, 0.f));
  o.u[2] = f2b(fmaxf(f.z, 0.f)); o.u[3] = f2b(fmaxf(f.w, 0.f));
  dst[k] = o.d;
}

// ---- h0 init: cast enc_hidden to bf16 into Hsb[0] ----
__global__ void h0_kernel(const float* __restrict__ eh, uint16_t* __restrict__ hb0) {
  int i = blockIdx.x * blockDim.x + threadIdx.x;   // 16384 threads x 4
  float4 f = ((const float4*)eh)[i];
  union { uint16_t u[4]; uint64_t d; } o;
  o.u[0] = f2b(f.x); o.u[1] = f2b(f.y); o.u[2] = f2b(f.z); o.u[3] = f2b(f.w);
  ((uint64_t*)hb0)[i] = o.d;
}

// ---- gi GEMM: gi = relu(emb)@W_ih^T + b_ih, row-major [4096][3072] f32 ----
__global__ __launch_bounds__(256) void gi_gemm_kernel(
    const uint16_t* __restrict__ A,    // [4096][1024]
    const uint16_t* __restrict__ Bm,   // [3072][1024]
    const float* __restrict__ bias,    // [3072]
    float* __restrict__ out) {         // [4096][3072]
  __shared__ uint16_t lA[128 * 32];
  __shared__ uint16_t lB[128 * 32];
  const int tid = threadIdx.x;
  const int lane = tid & 63;
  const int w = tid >> 6;
  const int wr = w >> 1, wc = w & 1;
  int flat = blockIdx.y * 24 + blockIdx.x;       // 768 blocks
  int nf = (flat & 7) * 96 + (flat >> 3);        // XCD swizzle (768 % 8 == 0)
  const int m0 = (nf / 24) * 128;
  const int n0 = (nf % 24) * 128;

  f32x4 acc[4][4];
#pragma unroll
  for (int mi = 0; mi < 4; ++mi)
#pragma unroll
    for (int ni = 0; ni < 4; ++ni) acc[mi][ni] = (f32x4){0, 0, 0, 0};

  const int srow = w * 16 + (lane >> 2);
  const int scol = (lane & 3) * 8;

  for (int k0 = 0; k0 < 1024; k0 += 32) {
    __syncthreads();
    g2l16(A + (size_t)(m0 + srow) * 1024 + k0 + scol,       &lA[w * 512]);
    g2l16(A + (size_t)(m0 + 64 + srow) * 1024 + k0 + scol,  &lA[2048 + w * 512]);
    g2l16(Bm + (size_t)(n0 + srow) * 1024 + k0 + scol,      &lB[w * 512]);
    g2l16(Bm + (size_t)(n0 + 64 + srow) * 1024 + k0 + scol, &lB[2048 + w * 512]);
    __syncthreads();
    bf16x8 a[4], b[4];
#pragma unroll
    for (int mi = 0; mi < 4; ++mi)
      a[mi] = *(const bf16x8*)&lA[(wr * 64 + mi * 16 + (lane & 15)) * 32 + (lane >> 4) * 8];
#pragma unroll
    for (int ni = 0; ni < 4; ++ni)
      b[ni] = *(const bf16x8*)&lB[(wc * 64 + ni * 16 + (lane & 15)) * 32 + (lane >> 4) * 8];
#pragma unroll
    for (int mi = 0; mi < 4; ++mi)
#pragma unroll
      for (int ni = 0; ni < 4; ++ni)
        acc[mi][ni] = __builtin_amdgcn_mfma_f32_16x16x32_bf16(a[mi], b[ni], acc[mi][ni], 0, 0, 0);
  }

#pragma unroll
  for (int ni = 0; ni < 4; ++ni) {
    int v = n0 + wc * 64 + ni * 16 + (lane & 15);
    float bv = bias[v];
#pragma unroll
    for (int mi = 0; mi < 4; ++mi) {
#pragma unroll
      for (int r = 0; r < 4; ++r) {
        int row = m0 + wr * 64 + mi * 16 + (lane >> 4) * 4 + r;
        out[(size_t)row * 3072 + v] = acc[mi][ni][r] + bv;
      }
    }
  }
}

// ---- one GRU step, gh-only: 256 blocks x 64 threads (1 wave) ----
__global__ __launch_bounds__(64) void step_kernel(
    const uint16_t* __restrict__ Whh_b,  // [3072][1024] bf16
    const float* __restrict__ gi,        // [4096][3072] f32 (incl b_ih)
    const float* __restrict__ b_hh,      // [3072]
    const float* __restrict__ h_cur,     // [64][1024] f32
    float* __restrict__ h_nxt,           // [64][1024] f32
    uint16_t* __restrict__ Hsb,          // [65][64][1024] bf16
    int t) {
  const int lane = threadIdx.x;
  const int l15 = lane & 15, kq = lane >> 4;
  const int rg = blockIdx.x >> 6, cs = blockIdx.x & 63;
  const int m0 = rg * 16, c0 = cs * 16;
  const int c = c0 + l15;

  float gr[4], gz[4], gn[4], hold[4];
#pragma unroll
  for (int r = 0; r < 4; ++r) {
    int m = m0 + kq * 4 + r;
    const float* gp = gi + (size_t)(t * 64 + m) * 3072;
    gr[r] = gp[c]; gz[r] = gp[1024 + c]; gn[r] = gp[2048 + c];
    hold[r] = h_cur[(size_t)m * 1024 + c];
  }

  const uint16_t* ap = Hsb + (size_t)(t * 64 + m0 + l15) * 1024 + kq * 8;
  const uint16_t* br = Whh_b + (size_t)(c) * 1024 + kq * 8;
  const uint16_t* bz = Whh_b + (size_t)(1024 + c) * 1024 + kq * 8;
  const uint16_t* bn = Whh_b + (size_t)(2048 + c) * 1024 + kq * 8;

  f32x4 ar = {0,0,0,0}, az = {0,0,0,0}, an = {0,0,0,0};
#pragma unroll
  for (int kk = 0; kk < 32; ++kk) {
    bf16x8 a = *(const bf16x8*)(ap + kk * 32);
    ar = __builtin_amdgcn_mfma_f32_16x16x32_bf16(a, *(const bf16x8*)(br + kk * 32), ar, 0, 0, 0);
    az = __builtin_amdgcn_mfma_f32_16x16x32_bf16(a, *(const bf16x8*)(bz + kk * 32), az, 0, 0, 0);
    an = __builtin_amdgcn_mfma_f32_16x16x32_bf16(a, *(const bf16x8*)(bn + kk * 32), an, 0, 0, 0);
  }

  float bhr = b_hh[c], bhz = b_hh[1024 + c], bhn = b_hh[2048 + c];
#pragma unroll
  for (int r = 0; r < 4; ++r) {
    int m = m0 + kq * 4 + r;
    float rg_ = 1.f / (1.f + __expf(-(gr[r] + ar[r] + bhr)));
    float zg  = 1.f / (1.f + __expf(-(gz[r] + az[r] + bhz)));
    float ng  = tanhf(gn[r] + rg_ * (an[r] + bhn));
    float hnew = (1.f - zg) * ng + zg * hold[r];
    h_nxt[(size_t)m * 1024 + c] = hnew;
    Hsb[(size_t)((t + 1) * 64 + m) * 1024 + c] = f2b(hnew);
  }
}

// ---- big output GEMM: 2D-chunked XCD swizzle, NT stores, row-partial epilogue ----
__global__ __launch_bounds__(256) void out_gemm_kernel(
    const uint16_t* __restrict__ A,    // [4096][1024]  (Hsb+65536)
    const uint16_t* __restrict__ Bm,   // [32000][1024]
    const float* __restrict__ bias,    // [32000]
    float* __restrict__ out,
    float2* __restrict__ px) {         // [4096][256] (rowmax, sumexp) per n-block
  __shared__ uint16_t lA[128 * 32];
  __shared__ uint16_t lB[128 * 32];
  __shared__ float smax[128][2];
  __shared__ float ssum[128][2];
  const int tid = threadIdx.x;
  const int lane = tid & 63;
  const int w = tid >> 6;
  const int wr = w >> 1, wc = w & 1;
  // 2D-chunked XCD mapping: xcd owns 4 contiguous m-tiles (A slice L2-resident),
  // sweeps n; all XCDs sweep n in lockstep -> B panel fetched from HBM ~once.
  int flat = blockIdx.y * 250 + blockIdx.x;        // 8000 blocks
  int xcd = flat & 7, i = flat >> 3;
  const int m0 = ((xcd << 2) | (i & 3)) * 128;     // m-tile 0..31
  const int n0 = (i >> 2) * 128;                   // n-tile 0..249

  f32x4 acc[4][4];
#pragma unroll
  for (int mi = 0; mi < 4; ++mi)
#pragma unroll
    for (int ni = 0; ni < 4; ++ni) acc[mi][ni] = (f32x4){0, 0, 0, 0};

  const int srow = w * 16 + (lane >> 2);
  const int scol = (lane & 3) * 8;

  for (int k0 = 0; k0 < 1024; k0 += 32) {
    __syncthreads();
    g2l16(A + (size_t)(m0 + srow) * 1024 + k0 + scol,       &lA[w * 512]);
    g2l16(A + (size_t)(m0 + 64 + srow) * 1024 + k0 + scol,  &lA[2048 + w * 512]);
    g2l16(Bm + (size_t)(n0 + srow) * 1024 + k0 + scol,      &lB[w * 512]);
    g2l16(Bm + (size_t)(n0 + 64 + srow) * 1024 + k0 + scol, &lB[2048 + w * 512]);
    __syncthreads();
    bf16x8 a[4], b[4];
#pragma unroll
    for (int mi = 0; mi < 4; ++mi)
      a[mi] = *(const bf16x8*)&lA[(wr * 64 + mi * 16 + (lane & 15)) * 32 + (lane >> 4) * 8];
#pragma unroll
    for (int ni = 0; ni < 4; ++ni)
      b[ni] = *(const bf16x8*)&lB[(wc * 64 + ni * 16 + (lane & 15)) * 32 + (lane >> 4) * 8];
#pragma unroll
    for (int mi = 0; mi < 4; ++mi)
#pragma unroll
      for (int ni = 0; ni < 4; ++ni)
        acc[mi][ni] = __builtin_amdgcn_mfma_f32_16x16x32_bf16(a[mi], b[ni], acc[mi][ni], 0, 0, 0);
  }

  // store logits + track per-row max over this block's 128 cols
  float bv[4], rmax[4][4], rsum[4][4];
#pragma unroll
  for (int mi = 0; mi < 4; ++mi)
#pragma unroll
    for (int r = 0; r < 4; ++r) { rmax[mi][r] = -3.4e38f; rsum[mi][r] = 0.f; }

#pragma unroll
  for (int ni = 0; ni < 4; ++ni) {
    int v = n0 + wc * 64 + ni * 16 + (lane & 15);
    bv[ni] = bias[v];
#pragma unroll
    for (int mi = 0; mi < 4; ++mi) {
#pragma unroll
      for (int r = 0; r < 4; ++r) {
        float x = acc[mi][ni][r] + bv[ni];
        int row = m0 + wr * 64 + mi * 16 + (lane >> 4) * 4 + r;  // row = t*64+b
        size_t off = (size_t)(row & 63) * (TSTEPS * (size_t)VOCAB)
                   + (size_t)(row >> 6) * VOCAB + v;
        __builtin_nontemporal_store(x, &out[off]);
        rmax[mi][r] = fmaxf(rmax[mi][r], x);
      }
    }
  }
  // reduce max over the 16-lane col group (lanes share rows within same kq)
#pragma unroll
  for (int mask = 1; mask < 16; mask <<= 1)
#pragma unroll
    for (int mi = 0; mi < 4; ++mi)
#pragma unroll
      for (int r = 0; r < 4; ++r)
        rmax[mi][r] = fmaxf(rmax[mi][r], __shfl_xor(rmax[mi][r], mask));
  // sumexp against the group max
#pragma unroll
  for (int ni = 0; ni < 4; ++ni)
#pragma unroll
    for (int mi = 0; mi < 4; ++mi)
#pragma unroll
      for (int r = 0; r < 4; ++r)
        rsum[mi][r] += __expf(acc[mi][ni][r] + bv[ni] - rmax[mi][r]);
#pragma unroll
  for (int mask = 1; mask < 16; mask <<= 1)
#pragma unroll
    for (int mi = 0; mi < 4; ++mi)
#pragma unroll
      for (int r = 0; r < 4; ++r)
        rsum[mi][r] += __shfl_xor(rsum[mi][r], mask);

  if ((lane & 15) == 0) {
    int kq = lane >> 4;
#pragma unroll
    for (int mi = 0; mi < 4; ++mi)
#pragma unroll
      for (int r = 0; r < 4; ++r) {
        int rl = wr * 64 + mi * 16 + kq * 4 + r;
        smax[rl][wc] = rmax[mi][r];
        ssum[rl][wc] = rsum[mi][r];
      }
  }
  __syncthreads();
  if (tid < 128) {
    float m0v = smax[tid][0], m1v = smax[tid][1];
    float M = fmaxf(m0v, m1v);
    float S = ssum[tid][0] * __expf(m0v - M) + ssum[tid][1] * __expf(m1v - M);
    px[(size_t)(m0 + tid) * 256 + (n0 >> 7)] = make_float2(M, S);
  }
}

// ---- fused lse-reduce + subtract (one read+write pass over logits) ----
__global__ __launch_bounds__(256) void lsefin_kernel(
    const float2* __restrict__ px, float* __restrict__ out) {
  const int tid = threadIdx.x;
  const int b = blockIdx.x >> 6, t = blockIdx.x & 63;   // out row = [b][t]
  const float2* p = px + (size_t)(t * 64 + b) * 256;
  float m = -3.4e38f, s = 0.f;
  if (tid < 250) { float2 v = p[tid]; m = v.x; s = v.y; }
#pragma unroll
  for (int off = 1; off < 64; off <<= 1) {
    float m2 = __shfl_xor(m, off);
    float s2 = __shfl_xor(s, off);
    float mn = fmaxf(m, m2);
    s = s * __expf(m - mn) + s2 * __expf(m2 - mn);
    m = mn;
  }
  __shared__ float sm[4], ss[4];
  if ((tid & 63) == 0) { sm[tid >> 6] = m; ss[tid >> 6] = s; }
  __syncthreads();
  float M = fmaxf(fmaxf(sm[0], sm[1]), fmaxf(sm[2], sm[3]));
  float S = ss[0] * __expf(sm[0] - M) + ss[1] * __expf(sm[1] - M)
          + ss[2] * __expf(sm[2] - M) + ss[3] * __expf(sm[3] - M);
  float lse = M + logf(S);
  float* row = out + (size_t)blockIdx.x * VOCAB;
  for (int i = tid * 4; i < VOCAB; i += 1024) {
    f32x4 x = *(const f32x4*)(row + i);
    x[0] -= lse; x[1] -= lse; x[2] -= lse; x[3] -= lse;
    __builtin_nontemporal_store(x, (f32x4*)(row + i));
  }
}

__global__ void hcopy_kernel(const float* __restrict__ h, float* __restrict__ out) {
  int i = blockIdx.x * blockDim.x + threadIdx.x;
  ((float4*)out)[i] = ((const float4*)h)[i];
}

extern "C" void kernel_launch(void* const* d_in, const int* in_sizes, int n_in,
                              void* d_out, int out_size, void* d_ws, size_t ws_size,
                              hipStream_t stream) {
  const float* enc_hidden = (const float*)d_in[1];   // [1,64,1024]
  const int* tgt          = (const int*)d_in[2];     // [64,64]
  const float* emb        = (const float*)d_in[3];   // [32000,1024]
  const float* W_ih       = (const float*)d_in[4];   // [3072,1024]
  const float* W_hh       = (const float*)d_in[5];   // [3072,1024]
  const float* b_ih       = (const float*)d_in[6];   // [3072]
  const float* b_hh       = (const float*)d_in[7];   // [3072]
  const float* W_out      = (const float*)d_in[8];   // [32000,1024]
  const float* b_out      = (const float*)d_in[9];   // [32000]
  float* out = (float*)d_out;

  char* ws = (char*)d_ws;
  // region [0, 65536000): gi (50.3 MB, live through recurrence) then Wout_b (cast after)
  float*    gi     = (float*)(ws);
  uint16_t* Wout_b = (uint16_t*)(ws);
  uint16_t* Wih_b  = (uint16_t*)(ws + 65536000);      // 6,291,456
  uint16_t* Whh_b  = (uint16_t*)(ws + 71827456);      // 6,291,456
  uint16_t* Xb     = (uint16_t*)(ws + 78118912);      // 8,388,608 (reused as px after gi_gemm)
  float2*   px     = (float2*)  (ws + 78118912);      // [4096][256] float2 = 8,388,608
  uint16_t* Hsb    = (uint16_t*)(ws + 86507520);      // 8,519,680  [65][64][1024]
  float*    hA     = (float*)   (ws + 95027200);      // 262,144
  float*    hB     = (float*)   (ws + 95289344);      // 262,144  (total 95,551,488)

  cast_bf16_kernel<<<2048, 256, 0, stream>>>(W_ih, Wih_b, 3072 * 1024 / 4);
  cast_bf16_kernel<<<2048, 256, 0, stream>>>(W_hh, Whh_b, 3072 * 1024 / 4);
  embed_kernel<<<4096, 256, 0, stream>>>(emb, tgt, Xb);
  h0_kernel<<<64, 256, 0, stream>>>(enc_hidden, Hsb);

  dim3 gg(24, 32);
  gi_gemm_kernel<<<gg, 256, 0, stream>>>(Xb, Wih_b, b_ih, gi);

  for (int t = 0; t < TSTEPS; ++t) {
    const float* hc = (t == 0) ? enc_hidden : ((t & 1) ? hA : hB);
    float* hn       = (t & 1) ? hB : hA;
    step_kernel<<<256, 64, 0, stream>>>(Whh_b, gi, b_hh, hc, hn, Hsb, t);
  }

  cast_bf16_kernel<<<2048, 256, 0, stream>>>(W_out, Wout_b, VOCAB * 1024 / 4);

  dim3 g(250, 32);
  out_gemm_kernel<<<g, 256, 0, stream>>>(Hsb + 65536, Wout_b, b_out, out, px);
  lsefin_kernel<<<4096, 256, 0, stream>>>(px, out);
  hcopy_kernel<<<64, 256, 0, stream>>>((TSTEPS & 1) ? hB : hA, out + 131072000ull);
}

// Round 6
// 1102.087 us; speedup vs baseline: 3.8610x; 1.0114x over previous
//
#include <hip/hip_runtime.h>
#include <hip/hip_bf16.h>
#include <stdint.h>

#define H 1024
#define BATCH 64
#define TSTEPS 64
#define VOCAB 32000

typedef __attribute__((ext_vector_type(8))) short bf16x8;
typedef __attribute__((ext_vector_type(4))) float f32x4;

__device__ __forceinline__ uint16_t f2b(float f) {
  union { float f; uint32_t u; } v; v.f = f;
  uint32_t u = v.u;
  return (uint16_t)((u + 0x7FFFu + ((u >> 16) & 1u)) >> 16);
}

__device__ __forceinline__ void g2l16(const uint16_t* g, uint16_t* l) {
  __builtin_amdgcn_global_load_lds((const __attribute__((address_space(1))) void*)(g),
                                   (__attribute__((address_space(3))) void*)(l), 16, 0, 0);
}

// ---- f32 -> bf16 cast (n4 = n/4) ----
__global__ void cast_bf16_kernel(const float* __restrict__ src, uint16_t* __restrict__ dst, int n4) {
  int i = blockIdx.x * blockDim.x + threadIdx.x;
  int stride = gridDim.x * blockDim.x;
  for (; i < n4; i += stride) {
    float4 f = ((const float4*)src)[i];
    union { uint16_t u[4]; uint64_t d; } o;
    o.u[0] = f2b(f.x); o.u[1] = f2b(f.y); o.u[2] = f2b(f.z); o.u[3] = f2b(f.w);
    ((uint64_t*)dst)[i] = o.d;
  }
}

// ---- embed + relu -> bf16, X[t*64+b][H] ----
__global__ void embed_kernel(const float* __restrict__ emb, const int* __restrict__ tgt,
                             uint16_t* __restrict__ X) {
  int i = blockIdx.x;            // 0..4095 = t*64+b
  int t = i >> 6, b = i & 63;
  int tok = (t == 0) ? 0 : tgt[b * TSTEPS + (t - 1)];
  const float4* src = (const float4*)(emb + (size_t)tok * H);
  uint64_t* dst = (uint64_t*)(X + (size_t)i * H);
  int k = threadIdx.x;           // 256 threads x 4 elems
  float4 f = src[k];
  union { uint16_t u[4]; uint64_t d; } o;
  o.u[0] = f2b(fmaxf(f.x, 0.f)); o.u[1] = f2b(fmaxf(f.y, 0.f));
  o.u[2] = f2b(fmaxf(f.z, 0.f)); o.u[3] = f2b(fmaxf(f.w, 0.f));
  dst[k] = o.d;
}

// ---- h0 init: cast enc_hidden to bf16 into Hsb[0] ----
__global__ void h0_kernel(const float* __restrict__ eh, uint16_t* __restrict__ hb0) {
  int i = blockIdx.x * blockDim.x + threadIdx.x;   // 16384 threads x 4
  float4 f = ((const float4*)eh)[i];
  union { uint16_t u[4]; uint64_t d; } o;
  o.u[0] = f2b(f.x); o.u[1] = f2b(f.y); o.u[2] = f2b(f.z); o.u[3] = f2b(f.w);
  ((uint64_t*)hb0)[i] = o.d;
}

// ---- gi GEMM: gi = relu(emb)@W_ih^T + b_ih, row-major [4096][3072] f32 ----
__global__ __launch_bounds__(256) void gi_gemm_kernel(
    const uint16_t* __restrict__ A,    // [4096][1024]
    const uint16_t* __restrict__ Bm,   // [3072][1024]
    const float* __restrict__ bias,    // [3072]
    float* __restrict__ out) {         // [4096][3072]
  __shared__ uint16_t lA[128 * 32];
  __shared__ uint16_t lB[128 * 32];
  const int tid = threadIdx.x;
  const int lane = tid & 63;
  const int w = tid >> 6;
  const int wr = w >> 1, wc = w & 1;
  int flat = blockIdx.y * 24 + blockIdx.x;       // 768 blocks
  int nf = (flat & 7) * 96 + (flat >> 3);        // XCD swizzle (768 % 8 == 0)
  const int m0 = (nf / 24) * 128;
  const int n0 = (nf % 24) * 128;

  f32x4 acc[4][4];
#pragma unroll
  for (int mi = 0; mi < 4; ++mi)
#pragma unroll
    for (int ni = 0; ni < 4; ++ni) acc[mi][ni] = (f32x4){0, 0, 0, 0};

  const int srow = w * 16 + (lane >> 2);
  const int scol = (lane & 3) * 8;

  for (int k0 = 0; k0 < 1024; k0 += 32) {
    __syncthreads();
    g2l16(A + (size_t)(m0 + srow) * 1024 + k0 + scol,       &lA[w * 512]);
    g2l16(A + (size_t)(m0 + 64 + srow) * 1024 + k0 + scol,  &lA[2048 + w * 512]);
    g2l16(Bm + (size_t)(n0 + srow) * 1024 + k0 + scol,      &lB[w * 512]);
    g2l16(Bm + (size_t)(n0 + 64 + srow) * 1024 + k0 + scol, &lB[2048 + w * 512]);
    __syncthreads();
    bf16x8 a[4], b[4];
#pragma unroll
    for (int mi = 0; mi < 4; ++mi)
      a[mi] = *(const bf16x8*)&lA[(wr * 64 + mi * 16 + (lane & 15)) * 32 + (lane >> 4) * 8];
#pragma unroll
    for (int ni = 0; ni < 4; ++ni)
      b[ni] = *(const bf16x8*)&lB[(wc * 64 + ni * 16 + (lane & 15)) * 32 + (lane >> 4) * 8];
#pragma unroll
    for (int mi = 0; mi < 4; ++mi)
#pragma unroll
      for (int ni = 0; ni < 4; ++ni)
        acc[mi][ni] = __builtin_amdgcn_mfma_f32_16x16x32_bf16(a[mi], b[ni], acc[mi][ni], 0, 0, 0);
  }

#pragma unroll
  for (int ni = 0; ni < 4; ++ni) {
    int v = n0 + wc * 64 + ni * 16 + (lane & 15);
    float bv = bias[v];
#pragma unroll
    for (int mi = 0; mi < 4; ++mi) {
#pragma unroll
      for (int r = 0; r < 4; ++r) {
        int row = m0 + wr * 64 + mi * 16 + (lane >> 4) * 4 + r;
        out[(size_t)row * 3072 + v] = acc[mi][ni][r] + bv;
      }
    }
  }
}

// ---- one GRU step, gh-only: 256 blocks x 64 threads (1 wave) ----
__global__ __launch_bounds__(64) void step_kernel(
    const uint16_t* __restrict__ Whh_b,  // [3072][1024] bf16
    const float* __restrict__ gi,        // [4096][3072] f32 (incl b_ih)
    const float* __restrict__ b_hh,      // [3072]
    const float* __restrict__ h_cur,     // [64][1024] f32
    float* __restrict__ h_nxt,           // [64][1024] f32
    uint16_t* __restrict__ Hsb,          // [65][64][1024] bf16
    int t) {
  const int lane = threadIdx.x;
  const int l15 = lane & 15, kq = lane >> 4;
  const int rg = blockIdx.x >> 6, cs = blockIdx.x & 63;
  const int m0 = rg * 16, c0 = cs * 16;
  const int c = c0 + l15;

  float gr[4], gz[4], gn[4], hold[4];
#pragma unroll
  for (int r = 0; r < 4; ++r) {
    int m = m0 + kq * 4 + r;
    const float* gp = gi + (size_t)(t * 64 + m) * 3072;
    gr[r] = gp[c]; gz[r] = gp[1024 + c]; gn[r] = gp[2048 + c];
    hold[r] = h_cur[(size_t)m * 1024 + c];
  }

  const uint16_t* ap = Hsb + (size_t)(t * 64 + m0 + l15) * 1024 + kq * 8;
  const uint16_t* br = Whh_b + (size_t)(c) * 1024 + kq * 8;
  const uint16_t* bz = Whh_b + (size_t)(1024 + c) * 1024 + kq * 8;
  const uint16_t* bn = Whh_b + (size_t)(2048 + c) * 1024 + kq * 8;

  f32x4 ar = {0,0,0,0}, az = {0,0,0,0}, an = {0,0,0,0};
#pragma unroll
  for (int kk = 0; kk < 32; ++kk) {
    bf16x8 a = *(const bf16x8*)(ap + kk * 32);
    ar = __builtin_amdgcn_mfma_f32_16x16x32_bf16(a, *(const bf16x8*)(br + kk * 32), ar, 0, 0, 0);
    az = __builtin_amdgcn_mfma_f32_16x16x32_bf16(a, *(const bf16x8*)(bz + kk * 32), az, 0, 0, 0);
    an = __builtin_amdgcn_mfma_f32_16x16x32_bf16(a, *(const bf16x8*)(bn + kk * 32), an, 0, 0, 0);
  }

  float bhr = b_hh[c], bhz = b_hh[1024 + c], bhn = b_hh[2048 + c];
#pragma unroll
  for (int r = 0; r < 4; ++r) {
    int m = m0 + kq * 4 + r;
    float rg_ = 1.f / (1.f + __expf(-(gr[r] + ar[r] + bhr)));
    float zg  = 1.f / (1.f + __expf(-(gz[r] + az[r] + bhz)));
    float ng  = tanhf(gn[r] + rg_ * (an[r] + bhn));
    float hnew = (1.f - zg) * ng + zg * hold[r];
    h_nxt[(size_t)m * 1024 + c] = hnew;
    Hsb[(size_t)((t + 1) * 64 + m) * 1024 + c] = f2b(hnew);
  }
}

// ---- big output GEMM: 2D-chunked XCD swizzle, NT stores, sum-exp epilogue ----
// No max-subtraction: |logit| <= |h|2*|w_row|2 + |b| ~ 32 << 88 (f32 exp-safe);
// worst-case row sum ~ 2.5e18 << f32 max. Saves 64 shfl + 16 VGPR vs max-tracking.
__global__ __launch_bounds__(256) void out_gemm_kernel(
    const uint16_t* __restrict__ A,    // [4096][1024]  (Hsb+65536)
    const uint16_t* __restrict__ Bm,   // [32000][1024]
    const float* __restrict__ bias,    // [32000]
    float* __restrict__ out,
    float* __restrict__ px) {          // [4096][256] sum-exp per n-block
  __shared__ uint16_t lA[128 * 32];
  __shared__ uint16_t lB[128 * 32];
  __shared__ float ssum[128][2];
  const int tid = threadIdx.x;
  const int lane = tid & 63;
  const int w = tid >> 6;
  const int wr = w >> 1, wc = w & 1;
  // 2D-chunked XCD mapping: xcd owns 4 contiguous m-tiles (A slice L2-resident),
  // sweeps n; all XCDs sweep n in lockstep -> B panel fetched from HBM ~once.
  int flat = blockIdx.y * 250 + blockIdx.x;        // 8000 blocks
  int xcd = flat & 7, i = flat >> 3;
  const int m0 = ((xcd << 2) | (i & 3)) * 128;     // m-tile 0..31
  const int n0 = (i >> 2) * 128;                   // n-tile 0..249

  f32x4 acc[4][4];
#pragma unroll
  for (int mi = 0; mi < 4; ++mi)
#pragma unroll
    for (int ni = 0; ni < 4; ++ni) acc[mi][ni] = (f32x4){0, 0, 0, 0};

  const int srow = w * 16 + (lane >> 2);
  const int scol = (lane & 3) * 8;

  for (int k0 = 0; k0 < 1024; k0 += 32) {
    __syncthreads();
    g2l16(A + (size_t)(m0 + srow) * 1024 + k0 + scol,       &lA[w * 512]);
    g2l16(A + (size_t)(m0 + 64 + srow) * 1024 + k0 + scol,  &lA[2048 + w * 512]);
    g2l16(Bm + (size_t)(n0 + srow) * 1024 + k0 + scol,      &lB[w * 512]);
    g2l16(Bm + (size_t)(n0 + 64 + srow) * 1024 + k0 + scol, &lB[2048 + w * 512]);
    __syncthreads();
    bf16x8 a[4], b[4];
#pragma unroll
    for (int mi = 0; mi < 4; ++mi)
      a[mi] = *(const bf16x8*)&lA[(wr * 64 + mi * 16 + (lane & 15)) * 32 + (lane >> 4) * 8];
#pragma unroll
    for (int ni = 0; ni < 4; ++ni)
      b[ni] = *(const bf16x8*)&lB[(wc * 64 + ni * 16 + (lane & 15)) * 32 + (lane >> 4) * 8];
#pragma unroll
    for (int mi = 0; mi < 4; ++mi)
#pragma unroll
      for (int ni = 0; ni < 4; ++ni)
        acc[mi][ni] = __builtin_amdgcn_mfma_f32_16x16x32_bf16(a[mi], b[ni], acc[mi][ni], 0, 0, 0);
  }

  // store logits + accumulate per-row sum(exp(x)) over this block's 128 cols
  float rsum[4][4];
#pragma unroll
  for (int mi = 0; mi < 4; ++mi)
#pragma unroll
    for (int r = 0; r < 4; ++r) rsum[mi][r] = 0.f;

#pragma unroll
  for (int ni = 0; ni < 4; ++ni) {
    int v = n0 + wc * 64 + ni * 16 + (lane & 15);
    float bv = bias[v];
#pragma unroll
    for (int mi = 0; mi < 4; ++mi) {
#pragma unroll
      for (int r = 0; r < 4; ++r) {
        float x = acc[mi][ni][r] + bv;
        int row = m0 + wr * 64 + mi * 16 + (lane >> 4) * 4 + r;  // row = t*64+b
        size_t off = (size_t)(row & 63) * (TSTEPS * (size_t)VOCAB)
                   + (size_t)(row >> 6) * VOCAB + v;
        __builtin_nontemporal_store(x, &out[off]);
        rsum[mi][r] += __expf(x);
      }
    }
  }
  // reduce sum over the 16-lane col group (same kq -> same rows)
#pragma unroll
  for (int mask = 1; mask < 16; mask <<= 1)
#pragma unroll
    for (int mi = 0; mi < 4; ++mi)
#pragma unroll
      for (int r = 0; r < 4; ++r)
        rsum[mi][r] += __shfl_xor(rsum[mi][r], mask);

  if ((lane & 15) == 0) {
    int kq = lane >> 4;
#pragma unroll
    for (int mi = 0; mi < 4; ++mi)
#pragma unroll
      for (int r = 0; r < 4; ++r)
        ssum[wr * 64 + mi * 16 + kq * 4 + r][wc] = rsum[mi][r];
  }
  __syncthreads();
  if (tid < 128)
    px[(size_t)(m0 + tid) * 256 + (n0 >> 7)] = ssum[tid][0] + ssum[tid][1];
}

// ---- fused lse-reduce + subtract (one read+write pass over logits) ----
__global__ __launch_bounds__(256) void lsefin_kernel(
    const float* __restrict__ px, float* __restrict__ out) {
  const int tid = threadIdx.x;
  const int b = blockIdx.x >> 6, t = blockIdx.x & 63;   // out row = [b][t]
  const float* p = px + (size_t)(t * 64 + b) * 256;
  float s = (tid < 250) ? p[tid] : 0.f;
#pragma unroll
  for (int off = 1; off < 64; off <<= 1) s += __shfl_xor(s, off);
  __shared__ float ss[4];
  if ((tid & 63) == 0) ss[tid >> 6] = s;
  __syncthreads();
  float lse = logf(ss[0] + ss[1] + ss[2] + ss[3]);
  float* row = out + (size_t)blockIdx.x * VOCAB;
  for (int i = tid * 4; i < VOCAB; i += 1024) {
    f32x4 x = *(const f32x4*)(row + i);
    x[0] -= lse; x[1] -= lse; x[2] -= lse; x[3] -= lse;
    __builtin_nontemporal_store(x, (f32x4*)(row + i));
  }
}

__global__ void hcopy_kernel(const float* __restrict__ h, float* __restrict__ out) {
  int i = blockIdx.x * blockDim.x + threadIdx.x;
  ((float4*)out)[i] = ((const float4*)h)[i];
}

extern "C" void kernel_launch(void* const* d_in, const int* in_sizes, int n_in,
                              void* d_out, int out_size, void* d_ws, size_t ws_size,
                              hipStream_t stream) {
  const float* enc_hidden = (const float*)d_in[1];   // [1,64,1024]
  const int* tgt          = (const int*)d_in[2];     // [64,64]
  const float* emb        = (const float*)d_in[3];   // [32000,1024]
  const float* W_ih       = (const float*)d_in[4];   // [3072,1024]
  const float* W_hh       = (const float*)d_in[5];   // [3072,1024]
  const float* b_ih       = (const float*)d_in[6];   // [3072]
  const float* b_hh       = (const float*)d_in[7];   // [3072]
  const float* W_out      = (const float*)d_in[8];   // [32000,1024]
  const float* b_out      = (const float*)d_in[9];   // [32000]
  float* out = (float*)d_out;

  char* ws = (char*)d_ws;
  // region [0, 65536000): gi (50.3 MB, live through recurrence) then Wout_b (cast after)
  float*    gi     = (float*)(ws);
  uint16_t* Wout_b = (uint16_t*)(ws);
  uint16_t* Wih_b  = (uint16_t*)(ws + 65536000);      // 6,291,456
  uint16_t* Whh_b  = (uint16_t*)(ws + 71827456);      // 6,291,456
  uint16_t* Xb     = (uint16_t*)(ws + 78118912);      // 8,388,608 (reused as px after gi_gemm)
  float*    px     = (float*)   (ws + 78118912);      // [4096][256] float = 4,194,304
  uint16_t* Hsb    = (uint16_t*)(ws + 86507520);      // 8,519,680  [65][64][1024]
  float*    hA     = (float*)   (ws + 95027200);      // 262,144
  float*    hB     = (float*)   (ws + 95289344);      // 262,144  (total 95,551,488)

  cast_bf16_kernel<<<2048, 256, 0, stream>>>(W_ih, Wih_b, 3072 * 1024 / 4);
  cast_bf16_kernel<<<2048, 256, 0, stream>>>(W_hh, Whh_b, 3072 * 1024 / 4);
  embed_kernel<<<4096, 256, 0, stream>>>(emb, tgt, Xb);
  h0_kernel<<<64, 256, 0, stream>>>(enc_hidden, Hsb);

  dim3 gg(24, 32);
  gi_gemm_kernel<<<gg, 256, 0, stream>>>(Xb, Wih_b, b_ih, gi);

  for (int t = 0; t < TSTEPS; ++t) {
    const float* hc = (t == 0) ? enc_hidden : ((t & 1) ? hA : hB);
    float* hn       = (t & 1) ? hB : hA;
    step_kernel<<<256, 64, 0, stream>>>(Whh_b, gi, b_hh, hc, hn, Hsb, t);
  }

  cast_bf16_kernel<<<2048, 256, 0, stream>>>(W_out, Wout_b, VOCAB * 1024 / 4);

  dim3 g(250, 32);
  out_gemm_kernel<<<g, 256, 0, stream>>>(Hsb + 65536, Wout_b, b_out, out, px);
  lsefin_kernel<<<4096, 256, 0, stream>>>(px, out);
  hcopy_kernel<<<64, 256, 0, stream>>>((TSTEPS & 1) ? hB : hA, out + 131072000ull);
}